// Round 7
// baseline (205.907 us; speedup 1.0000x reference)
//
#include <hip/hip_runtime.h>

// DifferenceCost, two-pass:
//  Pass A: transpose+convert fp32 [b][c][h][w] -> bf16 [b][h][w][c] in d_ws,
//          plus per-pixel sum-of-squares planes R2/T2 (on bf16-rounded values).
//  Pass B (corrcost7): wave = (b,h,wt16) x blockIdx.y=ig covering 3 i-rows.
//          launch_bounds(256,8) -> 8 waves/SIMD residency (R6 was capped at 4).
// Falls back to round-3 single-kernel path if ws too small.

#define B_N 4
#define C_N 128
#define H_N 96
#define W_N 192
#define TPLANE (H_N * W_N)                 // 18432
#define CPLANE ((size_t)C_N * TPLANE)

#define BF_SZ   ((size_t)B_N * TPLANE * C_N * 2)   // 18,874,368
#define REFB_OFF ((size_t)0)
#define TGTB_OFF BF_SZ
#define SQ_SZ   ((size_t)B_N * TPLANE * 4)
#define R2_OFF  (2 * BF_SZ)
#define T2_OFF  (R2_OFF + SQ_SZ)
#define WS_NEED (T2_OFF + SQ_SZ)                   // 38,338,560 B

using f32x4 = __attribute__((ext_vector_type(4))) float;
using s16x8 = __attribute__((ext_vector_type(8))) short;

__device__ __forceinline__ short f2bf(float x) {
    unsigned u = __builtin_bit_cast(unsigned, x);
    u = (u + 0x7fffu + ((u >> 16) & 1u)) >> 16;   // RNE; inputs finite
    return (short)(unsigned short)u;
}
__device__ __forceinline__ float bf2f(short s) {
    return __builtin_bit_cast(float, ((unsigned)(unsigned short)s) << 16);
}

// ---------------- Pass A: convert + transpose + squared sums ----------------
__global__ __launch_bounds__(256, 8)
void convert_kernel(const float* __restrict__ ref, const float* __restrict__ tgt,
                    unsigned char* __restrict__ ws)
{
    __shared__ unsigned int l32[64][65];

    const int tid = threadIdx.x;
    const int bid = blockIdx.x;
    const int wc  = bid % 3;
    const int h   = (bid / 3) % H_N;
    const int b   = bid / (3 * H_N);
    const int w0  = wc * 64;
    const int isT = blockIdx.y;

    const float* src = (isT ? tgt : ref) + (size_t)b * CPLANE + h * W_N + w0;
    unsigned char* dstB = ws + (isT ? TGTB_OFF : REFB_OFF);
    float* sq = (float*)(ws + (isT ? T2_OFF : R2_OFF));

    const int w  = tid & 63;
    const int cq = tid >> 6;
#pragma unroll
    for (int batch = 0; batch < 16; ++batch) {
        int cp = batch * 4 + cq;
        float v0 = src[(size_t)(2 * cp + 0) * TPLANE + w];
        float v1 = src[(size_t)(2 * cp + 1) * TPLANE + w];
        unsigned u = ((unsigned)(unsigned short)f2bf(v0))
                   | ((unsigned)(unsigned short)f2bf(v1) << 16);
        l32[w][cp] = u;
    }
    __syncthreads();

    const int cs = tid & 15;
#pragma unroll
    for (int pass = 0; pass < 4; ++pass) {
        int wr = pass * 16 + (tid >> 4);
        unsigned d[4];
        float s = 0.f;
#pragma unroll
        for (int k2 = 0; k2 < 4; ++k2) {
            unsigned u = l32[wr][cs * 4 + k2];
            d[k2] = u;
            float lo = __builtin_bit_cast(float, u << 16);
            float hi = __builtin_bit_cast(float, u & 0xffff0000u);
            s = fmaf(lo, lo, fmaf(hi, hi, s));
        }
        size_t pix = (size_t)(b * TPLANE + h * W_N + w0 + wr);
        *(uint4*)(dstB + (pix * C_N + cs * 8) * 2) = make_uint4(d[0], d[1], d[2], d[3]);
        s += __shfl_xor(s, 1); s += __shfl_xor(s, 2);
        s += __shfl_xor(s, 4); s += __shfl_xor(s, 8);
        if (cs == 0) sq[pix] = s;
    }
}

// ---------------- Pass B: wave=(b,h,wt), y=ig, 3 i-rows per wave ------------
#define MFMA_B16 __builtin_amdgcn_mfma_f32_16x16x32_bf16

#define LOADB6(ROW, BF, T2A)                                                   \
    {                                                                          \
        const int row_ = (ROW);                                                \
        if ((unsigned)row_ < (unsigned)H_N) {                                  \
            const short* tb_ = tgtb + ((size_t)(bT + row_ * W_N)) * C_N;       \
            const float* t2r_ = t2pl + row_ * W_N;                             \
            if (qok0) {                                                        \
                const short* p_ = tb_ + (size_t)q_t0 * C_N + grp * 8;          \
                BF[0] = *(const s16x8*)(p_);                                   \
                BF[1] = *(const s16x8*)(p_ + 32);                              \
                BF[2] = *(const s16x8*)(p_ + 64);                              \
                BF[3] = *(const s16x8*)(p_ + 96);                              \
                T2A[0] = t2r_[q_t0];                                           \
            } else {                                                           \
                BF[0] = BF[1] = BF[2] = BF[3] = (s16x8){0,0,0,0,0,0,0,0};      \
                T2A[0] = 0.f;                                                  \
            }                                                                  \
            if (qok1) {                                                        \
                const short* p_ = tb_ + (size_t)q_t1 * C_N + grp * 8;          \
                BF[4] = *(const s16x8*)(p_);                                   \
                BF[5] = *(const s16x8*)(p_ + 32);                              \
                BF[6] = *(const s16x8*)(p_ + 64);                              \
                BF[7] = *(const s16x8*)(p_ + 96);                              \
                T2A[1] = t2r_[q_t1];                                           \
            } else {                                                           \
                BF[4] = BF[5] = BF[6] = BF[7] = (s16x8){0,0,0,0,0,0,0,0};      \
                T2A[1] = 0.f;                                                  \
            }                                                                  \
        }                                                                      \
    }

#define STEP6(TT, ROW, BF, T2A)                                                \
    {                                                                          \
        const int row_ = (ROW);                                                \
        const bool rok_ = (unsigned)row_ < (unsigned)H_N;                      \
        f32x4 a0_ = {0.f,0.f,0.f,0.f}, a1_ = {0.f,0.f,0.f,0.f};                \
        if (rok_) {                                                            \
            a0_ = MFMA_B16(A0, BF[0], a0_, 0, 0, 0);                           \
            a0_ = MFMA_B16(A1, BF[1], a0_, 0, 0, 0);                           \
            a0_ = MFMA_B16(A2, BF[2], a0_, 0, 0, 0);                           \
            a0_ = MFMA_B16(A3, BF[3], a0_, 0, 0, 0);                           \
            a1_ = MFMA_B16(A0, BF[4], a1_, 0, 0, 0);                           \
            a1_ = MFMA_B16(A1, BF[5], a1_, 0, 0, 0);                           \
            a1_ = MFMA_B16(A2, BF[6], a1_, 0, 0, 0);                           \
            a1_ = MFMA_B16(A3, BF[7], a1_, 0, 0, 0);                           \
        }                                                                      \
        _Pragma("unroll")                                                      \
        for (int t_ = 0; t_ < 2; ++t_) {                                       \
            const float t2_ = T2A[t_];                                         \
            const bool qok_ = t_ ? qok1 : qok0;                                \
            const f32x4 ac_ = t_ ? a1_ : a0_;                                  \
            _Pragma("unroll")                                                  \
            for (int pp_ = 0; pp_ < 4; ++pp_) {                                \
                const int wl_ = grp * 4 + pp_;                                 \
                const int j_ = t_ * 16 + col - wl_ - 4;                        \
                float cs_ = r2v[pp_] + t2_ - 2.f * ac_[pp_];                   \
                float val_ = (rok_ && qok_)                                    \
                    ? __builtin_amdgcn_sqrtf(fmaxf(cs_, 0.f)) : 0.f;           \
                if ((unsigned)j_ < 9u) lds[wv][wl_][j_] = val_;                \
            }                                                                  \
        }                                                                      \
        float* ob_ = outb + (size_t)(TT) * 9 * TPLANE;                         \
        float v0_ = lds[wv][col][grp];                                         \
        float v1_ = lds[wv][col][4 + grp];                                     \
        ob_[so0] = v0_;                                                        \
        ob_[so1] = v1_;                                                        \
        if (lane < 16) ob_[so2] = lds[wv][col][8];                             \
    }

__global__ __launch_bounds__(256, 8)
void corrcost7(const unsigned char* __restrict__ ws, float* __restrict__ out)
{
    __shared__ float lds[4][16][12];   // [wave][w_local][j(+pad)] = 3 KiB

    const int tid  = threadIdx.x;
    const int lane = tid & 63;
    const int wv   = tid >> 6;
    const int col  = lane & 15;
    const int grp  = lane >> 4;

    // x: 1152 blocks = 8 XCDs x 144 (bijective chunked swizzle); y: ig (0..2)
    const int blk = blockIdx.x;
    const int swz = (blk & 7) * 144 + (blk >> 3);
    const int u   = swz * 4 + wv;          // (b*96+h)*12 + wt
    const int ig  = blockIdx.y;
    const int wt  = u % 12;
    const int v12 = u / 12;
    const int h   = v12 % 96;
    const int b   = v12 / 96;
    const int bT  = b * TPLANE;

    const int w0 = wt * 16;
    const int q0 = w0 - 8;
    const int q_t0 = q0 + col;
    const int q_t1 = q0 + 16 + col;
    const bool qok0 = (unsigned)q_t0 < (unsigned)W_N;
    const bool qok1 = (unsigned)q_t1 < (unsigned)W_N;

    // A fragments + R2 (once per wave)
    const short* refp = (const short*)(ws + REFB_OFF)
        + ((size_t)(bT + h * W_N + w0 + col)) * C_N + grp * 8;
    const s16x8 A0 = *(const s16x8*)(refp);
    const s16x8 A1 = *(const s16x8*)(refp + 32);
    const s16x8 A2 = *(const s16x8*)(refp + 64);
    const s16x8 A3 = *(const s16x8*)(refp + 96);

    const float* r2p = (const float*)(ws + R2_OFF) + bT + h * W_N + w0;
    const f32x4 r2v = *(const f32x4*)(r2p + grp * 4);

    const short* tgtb = (const short*)(ws + TGTB_OFF);
    const float* t2pl = (const float*)(ws + T2_OFF) + bT;

    float* outb = out + (size_t)b * 81 * TPLANE + (size_t)ig * 27 * TPLANE
                + h * W_N + w0;
    const size_t so0 = (size_t)grp * TPLANE + col;        // j=grp
    const size_t so1 = (size_t)(4 + grp) * TPLANE + col;  // j=4+grp
    const size_t so2 = (size_t)8 * TPLANE + col;          // j=8

    const int rowbase = h + ig * 3 - 4;

    s16x8 Ba[8]; float t2a[2] = {0.f, 0.f};
    s16x8 Bb[8]; float t2b[2] = {0.f, 0.f};

    LOADB6(rowbase + 0, Ba, t2a);
    LOADB6(rowbase + 1, Bb, t2b);
    STEP6(0, rowbase + 0, Ba, t2a);
    LOADB6(rowbase + 2, Ba, t2a);
    STEP6(1, rowbase + 1, Bb, t2b);
    STEP6(2, rowbase + 2, Ba, t2a);
}

// ---------------- Fallback (round-3 kernel, used if ws too small) ----------
__global__ __launch_bounds__(256, 4)
void corrcost3(const float* __restrict__ ref,
               const float* __restrict__ tgt,
               float* __restrict__ out)
{
    const int tid  = threadIdx.x;
    const int lane = tid & 63;
    const int wv   = tid >> 6;
    const int bid = blockIdx.x;
    const int swz = (bid & 7) * 1296 + (bid >> 3);
    const int u   = swz * 4 + wv;
    const int i   = u % 9;
    const int v9  = u / 9;
    const int wt  = v9 % 12;
    const int v12 = v9 / 12;
    const int h   = v12 % 96;
    const int b   = v12 / 96;
    const int w0  = wt * 16;
    const int q0  = w0 - 8;
    const int row = h + i - 4;
    const bool rok = (unsigned)row < (unsigned)H_N;

    const float* ref_b = ref + (size_t)b * CPLANE;
    const float* tgt_b = tgt + (size_t)b * CPLANE;
    float* out_b = out + (size_t)b * 81 * TPLANE;
    const int col = lane & 15;
    const int ke  = (lane >> 4) * 8;

    s16x8 A[4];
    float r2p = 0.f;
    const float* aptr = ref_b + (size_t)ke * TPLANE + h * W_N + w0 + col;
#pragma unroll
    for (int kc = 0; kc < 4; ++kc) {
#pragma unroll
        for (int e = 0; e < 8; ++e) {
            float v = aptr[(size_t)(kc * 32 + e) * TPLANE];
            short s = f2bf(v);
            float vb = bf2f(s);
            r2p = fmaf(vb, vb, r2p);
            A[kc][e] = s;
        }
    }
    r2p += __shfl_xor(r2p, 16);
    r2p += __shfl_xor(r2p, 32);
    float r2r[4];
#pragma unroll
    for (int pp = 0; pp < 4; ++pp)
        r2r[pp] = __shfl(r2p, (lane >> 4) * 4 + pp);

    f32x4 acc0 = {0.f, 0.f, 0.f, 0.f}, acc1 = acc0;
    float t20 = 0.f, t21 = 0.f;
    if (rok) {
        const float* bbase = tgt_b + (size_t)ke * TPLANE + (size_t)row * W_N;
#pragma unroll
        for (int t = 0; t < 2; ++t) {
            const int q = q0 + t * 16 + col;
            const bool qok = (unsigned)q < (unsigned)W_N;
            const float* bptr = bbase + q;
            s16x8 Bf[4];
            float t2p = 0.f;
#pragma unroll
            for (int kc = 0; kc < 4; ++kc) {
#pragma unroll
                for (int e = 0; e < 8; ++e) {
                    float v = qok ? bptr[(size_t)(kc * 32 + e) * TPLANE] : 0.f;
                    short s = f2bf(v);
                    float vb = bf2f(s);
                    t2p = fmaf(vb, vb, t2p);
                    Bf[kc][e] = s;
                }
            }
            t2p += __shfl_xor(t2p, 16);
            t2p += __shfl_xor(t2p, 32);
            if (t == 0) {
                t20 = t2p;
#pragma unroll
                for (int kc = 0; kc < 4; ++kc)
                    acc0 = MFMA_B16(A[kc], Bf[kc], acc0, 0, 0, 0);
            } else {
                t21 = t2p;
#pragma unroll
                for (int kc = 0; kc < 4; ++kc)
                    acc1 = MFMA_B16(A[kc], Bf[kc], acc1, 0, 0, 0);
            }
        }
    }
#pragma unroll
    for (int t = 0; t < 2; ++t) {
        const int q = q0 + t * 16 + col;
        const bool qok = (unsigned)q < (unsigned)W_N;
        const f32x4 a = t ? acc1 : acc0;
        const float t2 = t ? t21 : t20;
#pragma unroll
        for (int pp = 0; pp < 4; ++pp) {
            const int wl = (lane >> 4) * 4 + pp;
            const int j  = q - (w0 + wl) + 4;
            if ((unsigned)j < 9u) {
                float val = 0.f;
                if (rok && qok) {
                    float cs = r2r[pp] + t2 - 2.f * a[pp];
                    val = cs > 0.f ? sqrtf(cs) : 0.f;
                }
                out_b[(size_t)(i * 9 + j) * TPLANE + h * W_N + w0 + wl] = val;
            }
        }
    }
}

extern "C" void kernel_launch(void* const* d_in, const int* in_sizes, int n_in,
                              void* d_out, int out_size, void* d_ws, size_t ws_size,
                              hipStream_t stream) {
    const float* ref = (const float*)d_in[0];
    const float* tgt = (const float*)d_in[1];
    float* out = (float*)d_out;

    if (ws_size >= WS_NEED && d_ws != nullptr) {
        unsigned char* ws = (unsigned char*)d_ws;
        convert_kernel<<<dim3(3 * H_N * B_N, 2), dim3(256), 0, stream>>>(ref, tgt, ws);
        corrcost7<<<dim3(1152, 3), dim3(256), 0, stream>>>(ws, out);
    } else {
        corrcost3<<<dim3(10368), dim3(256), 0, stream>>>(ref, tgt, out);
    }
}

// Round 8
// 51.094 us; speedup vs baseline: 4.0300x; 4.0300x over previous
//
#include <hip/hip_runtime.h>

// DifferenceCost, two-pass, fragment-major workspace:
//  Pass A: fp32 [b][c][h][w] -> bf16 MFMA-fragment layout
//          frag[b][row][qtile(12)][kc(4)][lane(64)] (16B per lane), plus
//          per-pixel sum-of-squares planes R2/T2 (on bf16-rounded values).
//          => every pass-B operand load is one fully-coalesced 1KB dwordx4.
//  Pass B (corrcost8): wave = (b,h,wt16) x blockIdx.y=ig covering 3 i-rows.
//          Per row: 3 aligned q-tiles (wt-1,wt,wt+1) x 4 kc MFMAs.
//          cost = sqrt(max(R2+T2-2X,0)); extract via tiny LDS transpose.
// Falls back to round-3 single-kernel path if ws too small.

#define B_N 4
#define C_N 128
#define H_N 96
#define W_N 192
#define TPLANE (H_N * W_N)                 // 18432
#define CPLANE ((size_t)C_N * TPLANE)

#define FRAG_ROW_SZ ((size_t)12 * 4 * 1024)          // 49152 B per (b,row)
#define BF_SZ   ((size_t)B_N * H_N * FRAG_ROW_SZ)    // 18,874,368
#define REFF_OFF ((size_t)0)
#define TGTF_OFF BF_SZ
#define SQ_SZ   ((size_t)B_N * TPLANE * 4)
#define R2_OFF  (2 * BF_SZ)
#define T2_OFF  (R2_OFF + SQ_SZ)
#define WS_NEED (T2_OFF + SQ_SZ)                     // 38,338,560 B

using f32x4 = __attribute__((ext_vector_type(4))) float;
using s16x8 = __attribute__((ext_vector_type(8))) short;

__device__ __forceinline__ short f2bf(float x) {
    unsigned u = __builtin_bit_cast(unsigned, x);
    u = (u + 0x7fffu + ((u >> 16) & 1u)) >> 16;   // RNE; inputs finite
    return (short)(unsigned short)u;
}
__device__ __forceinline__ float bf2f(short s) {
    return __builtin_bit_cast(float, ((unsigned)(unsigned short)s) << 16);
}

// ---------------- Pass A: convert + fragment-major store + squared sums ----
__global__ __launch_bounds__(256, 4)
void convert_frag(const float* __restrict__ ref, const float* __restrict__ tgt,
                  unsigned char* __restrict__ ws)
{
    __shared__ unsigned int l32[64][65];   // [w][c-pair], stride 65 -> no conflicts

    const int tid = threadIdx.x;
    const int bid = blockIdx.x;
    const int wc  = bid % 3;               // which 64-w chunk
    const int h   = (bid / 3) % H_N;
    const int b   = bid / (3 * H_N);
    const int w0  = wc * 64;
    const int isT = blockIdx.y;

    const float* src = (isT ? tgt : ref) + (size_t)b * CPLANE + h * W_N + w0;
    unsigned char* dstF = ws + (isT ? TGTF_OFF : REFF_OFF);
    float* sq = (float*)(ws + (isT ? T2_OFF : R2_OFF));

    // phase 1: coalesced fp32 read, convert, pack pairs into LDS
    const int w  = tid & 63;
    const int cq = tid >> 6;
#pragma unroll
    for (int batch = 0; batch < 16; ++batch) {
        int cp = batch * 4 + cq;
        float v0 = src[(size_t)(2 * cp + 0) * TPLANE + w];
        float v1 = src[(size_t)(2 * cp + 1) * TPLANE + w];
        unsigned u = ((unsigned)(unsigned short)f2bf(v0))
                   | ((unsigned)(unsigned short)f2bf(v1) << 16);
        l32[w][cp] = u;
    }
    __syncthreads();

    // phase 2: fragment-major store. idx -> (qt_l, kc, lane); each wave-iter
    // writes 1KB contiguous (lane*16).
#pragma unroll
    for (int it = 0; it < 4; ++it) {
        int idx   = it * 256 + tid;        // 0..1023
        int lane2 = idx & 63;
        int kc    = (idx >> 6) & 3;
        int qt_l  = idx >> 8;              // 0..3
        int w_l   = qt_l * 16 + (lane2 & 15);
        int cp0   = kc * 16 + (lane2 >> 4) * 4;
        uint4 d = make_uint4(l32[w_l][cp0], l32[w_l][cp0 + 1],
                             l32[w_l][cp0 + 2], l32[w_l][cp0 + 3]);
        int qt = wc * 4 + qt_l;
        size_t off = (((size_t)(b * H_N + h) * 12 + qt) * 4 + kc) * 1024
                   + (size_t)lane2 * 16;
        *(uint4*)(dstF + off) = d;
    }

    // phase 3: per-pixel sum of squares (bf16-rounded)
    const int cs = tid & 15;
#pragma unroll
    for (int pass = 0; pass < 4; ++pass) {
        int wr = pass * 16 + (tid >> 4);
        float s = 0.f;
#pragma unroll
        for (int k2 = 0; k2 < 4; ++k2) {
            unsigned u = l32[wr][cs * 4 + k2];
            float lo = __builtin_bit_cast(float, u << 16);
            float hi = __builtin_bit_cast(float, u & 0xffff0000u);
            s = fmaf(lo, lo, fmaf(hi, hi, s));
        }
        s += __shfl_xor(s, 1); s += __shfl_xor(s, 2);
        s += __shfl_xor(s, 4); s += __shfl_xor(s, 8);
        if (cs == 0) sq[(size_t)(b * TPLANE + h * W_N + w0 + wr)] = s;
    }
}

// ---------------- Pass B: wave=(b,h,wt), y=ig, 3 i-rows, 3 q-tiles ---------
#define MFMA_B16 __builtin_amdgcn_mfma_f32_16x16x32_bf16

__global__ __launch_bounds__(256, 4)
void corrcost8(const unsigned char* __restrict__ ws, float* __restrict__ out)
{
    __shared__ float lds[4][16][12];   // [wave][w_local][j(+pad)] = 3 KiB

    const int tid  = threadIdx.x;
    const int lane = tid & 63;
    const int wv   = tid >> 6;
    const int col  = lane & 15;
    const int grp  = lane >> 4;

    // x: 1152 blocks = 8 XCDs x 144 (bijective chunked swizzle); y: ig (0..2)
    const int blk = blockIdx.x;
    const int swz = (blk & 7) * 144 + (blk >> 3);
    const int u   = swz * 4 + wv;          // (b*96+h)*12 + wt
    const int ig  = blockIdx.y;
    const int wt  = u % 12;
    const int v12 = u / 12;
    const int h   = v12 % 96;
    const int b   = v12 / 96;
    const int bT  = b * TPLANE;

    const int w0 = wt * 16;

    // A fragments: 4 fully-coalesced 1KB loads
    const unsigned char* fA = ws + REFF_OFF
        + ((size_t)(b * H_N + h) * 12 + wt) * 4 * 1024 + (size_t)lane * 16;
    const s16x8 A0 = *(const s16x8*)(fA);
    const s16x8 A1 = *(const s16x8*)(fA + 1024);
    const s16x8 A2 = *(const s16x8*)(fA + 2048);
    const s16x8 A3 = *(const s16x8*)(fA + 3072);

    const float* r2p = (const float*)(ws + R2_OFF) + bT + h * W_N + w0;
    const f32x4 r2v = *(const f32x4*)(r2p + grp * 4);

    const float* t2pl = (const float*)(ws + T2_OFF) + bT;

    float* outb = out + (size_t)b * 81 * TPLANE + (size_t)ig * 27 * TPLANE
                + h * W_N + w0;
    const size_t so0 = (size_t)grp * TPLANE + col;        // j=grp
    const size_t so1 = (size_t)(4 + grp) * TPLANE + col;  // j=4+grp
    const size_t so2 = (size_t)8 * TPLANE + col;          // j=8

    const int rowbase = h + ig * 3 - 4;
    const bool dok0 = (wt >= 1);
    const bool dok1 = true;
    const bool dok2 = (wt <= 10);

#pragma unroll
    for (int tt = 0; tt < 3; ++tt) {
        const int row = rowbase + tt;
        const bool rok = (unsigned)row < (unsigned)H_N;

        f32x4 acc[3];
        acc[0] = (f32x4){0.f, 0.f, 0.f, 0.f};
        acc[1] = acc[0];
        acc[2] = acc[0];
        float t2v[3] = {0.f, 0.f, 0.f};

        if (rok) {                          // wave-uniform
            const unsigned char* fB = ws + TGTF_OFF
                + (size_t)(b * H_N + row) * FRAG_ROW_SZ + (size_t)lane * 16;
            const float* t2r = t2pl + row * W_N;
#pragma unroll
            for (int d = 0; d < 3; ++d) {
                const int qt = wt - 1 + d;
                const bool dok = d == 0 ? dok0 : (d == 1 ? dok1 : dok2);
                if (dok) {                  // wave-uniform
                    const unsigned char* p = fB + (size_t)qt * 4096;
                    const s16x8 B0 = *(const s16x8*)(p);
                    const s16x8 B1 = *(const s16x8*)(p + 1024);
                    const s16x8 B2 = *(const s16x8*)(p + 2048);
                    const s16x8 B3 = *(const s16x8*)(p + 3072);
                    t2v[d] = t2r[qt * 16 + col];
                    acc[d] = MFMA_B16(A0, B0, acc[d], 0, 0, 0);
                    acc[d] = MFMA_B16(A1, B1, acc[d], 0, 0, 0);
                    acc[d] = MFMA_B16(A2, B2, acc[d], 0, 0, 0);
                    acc[d] = MFMA_B16(A3, B3, acc[d], 0, 0, 0);
                }
            }
        }

        // extract: D col = lane&15 (q within tile), D row = grp*4+pp (w)
#pragma unroll
        for (int d = 0; d < 3; ++d) {
            const bool dok = d == 0 ? dok0 : (d == 1 ? dok1 : dok2);
#pragma unroll
            for (int pp = 0; pp < 4; ++pp) {
                const int wl = grp * 4 + pp;
                const int j  = 16 * (d - 1) + col - wl + 4;
                if ((unsigned)j < 9u) {
                    float val = 0.f;
                    if (rok && dok) {
                        float cs = r2v[pp] + t2v[d] - 2.f * acc[d][pp];
                        val = __builtin_amdgcn_sqrtf(fmaxf(cs, 0.f));
                    }
                    lds[wv][wl][j] = val;
                }
            }
        }

        float* ob = outb + (size_t)tt * 9 * TPLANE;
        float v0 = lds[wv][col][grp];
        float v1 = lds[wv][col][4 + grp];
        ob[so0] = v0;
        ob[so1] = v1;
        if (lane < 16) ob[so2] = lds[wv][col][8];
    }
}

// ---------------- Fallback (round-3 kernel, used if ws too small) ----------
__global__ __launch_bounds__(256, 4)
void corrcost3(const float* __restrict__ ref,
               const float* __restrict__ tgt,
               float* __restrict__ out)
{
    const int tid  = threadIdx.x;
    const int lane = tid & 63;
    const int wv   = tid >> 6;
    const int bid = blockIdx.x;
    const int swz = (bid & 7) * 1296 + (bid >> 3);
    const int u   = swz * 4 + wv;
    const int i   = u % 9;
    const int v9  = u / 9;
    const int wt  = v9 % 12;
    const int v12 = v9 / 12;
    const int h   = v12 % 96;
    const int b   = v12 / 96;
    const int w0  = wt * 16;
    const int q0  = w0 - 8;
    const int row = h + i - 4;
    const bool rok = (unsigned)row < (unsigned)H_N;

    const float* ref_b = ref + (size_t)b * CPLANE;
    const float* tgt_b = tgt + (size_t)b * CPLANE;
    float* out_b = out + (size_t)b * 81 * TPLANE;
    const int col = lane & 15;
    const int ke  = (lane >> 4) * 8;

    s16x8 A[4];
    float r2p = 0.f;
    const float* aptr = ref_b + (size_t)ke * TPLANE + h * W_N + w0 + col;
#pragma unroll
    for (int kc = 0; kc < 4; ++kc) {
#pragma unroll
        for (int e = 0; e < 8; ++e) {
            float v = aptr[(size_t)(kc * 32 + e) * TPLANE];
            short s = f2bf(v);
            float vb = bf2f(s);
            r2p = fmaf(vb, vb, r2p);
            A[kc][e] = s;
        }
    }
    r2p += __shfl_xor(r2p, 16);
    r2p += __shfl_xor(r2p, 32);
    float r2r[4];
#pragma unroll
    for (int pp = 0; pp < 4; ++pp)
        r2r[pp] = __shfl(r2p, (lane >> 4) * 4 + pp);

    f32x4 acc0 = {0.f, 0.f, 0.f, 0.f}, acc1 = acc0;
    float t20 = 0.f, t21 = 0.f;
    if (rok) {
        const float* bbase = tgt_b + (size_t)ke * TPLANE + (size_t)row * W_N;
#pragma unroll
        for (int t = 0; t < 2; ++t) {
            const int q = q0 + t * 16 + col;
            const bool qok = (unsigned)q < (unsigned)W_N;
            const float* bptr = bbase + q;
            s16x8 Bf[4];
            float t2p = 0.f;
#pragma unroll
            for (int kc = 0; kc < 4; ++kc) {
#pragma unroll
                for (int e = 0; e < 8; ++e) {
                    float v = qok ? bptr[(size_t)(kc * 32 + e) * TPLANE] : 0.f;
                    short s = f2bf(v);
                    float vb = bf2f(s);
                    t2p = fmaf(vb, vb, t2p);
                    Bf[kc][e] = s;
                }
            }
            t2p += __shfl_xor(t2p, 16);
            t2p += __shfl_xor(t2p, 32);
            if (t == 0) {
                t20 = t2p;
#pragma unroll
                for (int kc = 0; kc < 4; ++kc)
                    acc0 = MFMA_B16(A[kc], Bf[kc], acc0, 0, 0, 0);
            } else {
                t21 = t2p;
#pragma unroll
                for (int kc = 0; kc < 4; ++kc)
                    acc1 = MFMA_B16(A[kc], Bf[kc], acc1, 0, 0, 0);
            }
        }
    }
#pragma unroll
    for (int t = 0; t < 2; ++t) {
        const int q = q0 + t * 16 + col;
        const bool qok = (unsigned)q < (unsigned)W_N;
        const f32x4 a = t ? acc1 : acc0;
        const float t2 = t ? t21 : t20;
#pragma unroll
        for (int pp = 0; pp < 4; ++pp) {
            const int wl = (lane >> 4) * 4 + pp;
            const int j  = q - (w0 + wl) + 4;
            if ((unsigned)j < 9u) {
                float val = 0.f;
                if (rok && qok) {
                    float cs = r2r[pp] + t2 - 2.f * a[pp];
                    val = cs > 0.f ? sqrtf(cs) : 0.f;
                }
                out_b[(size_t)(i * 9 + j) * TPLANE + h * W_N + w0 + wl] = val;
            }
        }
    }
}

extern "C" void kernel_launch(void* const* d_in, const int* in_sizes, int n_in,
                              void* d_out, int out_size, void* d_ws, size_t ws_size,
                              hipStream_t stream) {
    const float* ref = (const float*)d_in[0];
    const float* tgt = (const float*)d_in[1];
    float* out = (float*)d_out;

    if (ws_size >= WS_NEED && d_ws != nullptr) {
        unsigned char* ws = (unsigned char*)d_ws;
        convert_frag<<<dim3(3 * H_N * B_N, 2), dim3(256), 0, stream>>>(ref, tgt, ws);
        corrcost8<<<dim3(1152, 3), dim3(256), 0, stream>>>(ws, out);
    } else {
        corrcost3<<<dim3(10368), dim3(256), 0, stream>>>(ref, tgt, out);
    }
}

// Round 9
// 48.732 us; speedup vs baseline: 4.2253x; 1.0485x over previous
//
#include <hip/hip_runtime.h>

// DifferenceCost, two-pass, fragment-major workspace:
//  Pass A: fp32 [b][c][h][w] -> bf16 MFMA-fragment layout
//          frag[b][row][qtile(12)][kc(4)][lane(64)] (16B per lane), plus
//          per-pixel sum-of-squares planes R2/T2 (on bf16-rounded values).
//  Pass B (corrcost9): block = (b,h,wt-group-of-4) x ig. Per row, the 4 waves
//          cooperatively stage the 6-qtile union into LDS via
//          global_load_lds (1KB DMA per instr), then each wave ds_read_b128s
//          its 12 fragments. cost = sqrt(max(R2+T2-2X,0)).
// Falls back to round-3 single-kernel path if ws too small.

#define B_N 4
#define C_N 128
#define H_N 96
#define W_N 192
#define TPLANE (H_N * W_N)                 // 18432
#define CPLANE ((size_t)C_N * TPLANE)

#define FRAG_ROW_SZ ((size_t)12 * 4 * 1024)          // 49152 B per (b,row)
#define BF_SZ   ((size_t)B_N * H_N * FRAG_ROW_SZ)    // 18,874,368
#define REFF_OFF ((size_t)0)
#define TGTF_OFF BF_SZ
#define SQ_SZ   ((size_t)B_N * TPLANE * 4)
#define R2_OFF  (2 * BF_SZ)
#define T2_OFF  (R2_OFF + SQ_SZ)
#define WS_NEED (T2_OFF + SQ_SZ)                     // 38,338,560 B

using f32x4 = __attribute__((ext_vector_type(4))) float;
using s16x8 = __attribute__((ext_vector_type(8))) short;

typedef const __attribute__((address_space(1))) void* gas1_t;
typedef __attribute__((address_space(3))) void* las3_t;
#define GLL16(gp, lp) __builtin_amdgcn_global_load_lds((gas1_t)(gp), (las3_t)(lp), 16, 0, 0)

__device__ __forceinline__ short f2bf(float x) {
    unsigned u = __builtin_bit_cast(unsigned, x);
    u = (u + 0x7fffu + ((u >> 16) & 1u)) >> 16;   // RNE; inputs finite
    return (short)(unsigned short)u;
}
__device__ __forceinline__ float bf2f(short s) {
    return __builtin_bit_cast(float, ((unsigned)(unsigned short)s) << 16);
}

// ---------------- Pass A: convert + fragment-major store + squared sums ----
__global__ __launch_bounds__(256, 4)
void convert_frag(const float* __restrict__ ref, const float* __restrict__ tgt,
                  unsigned char* __restrict__ ws)
{
    __shared__ unsigned int l32[64][65];   // [w][c-pair], stride 65 -> no conflicts

    const int tid = threadIdx.x;
    const int bid = blockIdx.x;
    const int wc  = bid % 3;               // which 64-w chunk
    const int h   = (bid / 3) % H_N;
    const int b   = bid / (3 * H_N);
    const int w0  = wc * 64;
    const int isT = blockIdx.y;

    const float* src = (isT ? tgt : ref) + (size_t)b * CPLANE + h * W_N + w0;
    unsigned char* dstF = ws + (isT ? TGTF_OFF : REFF_OFF);
    float* sq = (float*)(ws + (isT ? T2_OFF : R2_OFF));

    // phase 1: coalesced fp32 read, convert, pack pairs into LDS
    const int w  = tid & 63;
    const int cq = tid >> 6;
#pragma unroll
    for (int batch = 0; batch < 16; ++batch) {
        int cp = batch * 4 + cq;
        float v0 = src[(size_t)(2 * cp + 0) * TPLANE + w];
        float v1 = src[(size_t)(2 * cp + 1) * TPLANE + w];
        unsigned u = ((unsigned)(unsigned short)f2bf(v0))
                   | ((unsigned)(unsigned short)f2bf(v1) << 16);
        l32[w][cp] = u;
    }
    __syncthreads();

    // phase 2: fragment-major store; each wave-iter writes 1KB contiguous.
#pragma unroll
    for (int it = 0; it < 4; ++it) {
        int idx   = it * 256 + tid;        // 0..1023
        int lane2 = idx & 63;
        int kc    = (idx >> 6) & 3;
        int qt_l  = idx >> 8;              // 0..3
        int w_l   = qt_l * 16 + (lane2 & 15);
        int cp0   = kc * 16 + (lane2 >> 4) * 4;
        uint4 d = make_uint4(l32[w_l][cp0], l32[w_l][cp0 + 1],
                             l32[w_l][cp0 + 2], l32[w_l][cp0 + 3]);
        int qt = wc * 4 + qt_l;
        size_t off = (((size_t)(b * H_N + h) * 12 + qt) * 4 + kc) * 1024
                   + (size_t)lane2 * 16;
        *(uint4*)(dstF + off) = d;
    }

    // phase 3: per-pixel sum of squares (bf16-rounded)
    const int cs = tid & 15;
#pragma unroll
    for (int pass = 0; pass < 4; ++pass) {
        int wr = pass * 16 + (tid >> 4);
        float s = 0.f;
#pragma unroll
        for (int k2 = 0; k2 < 4; ++k2) {
            unsigned u = l32[wr][cs * 4 + k2];
            float lo = __builtin_bit_cast(float, u << 16);
            float hi = __builtin_bit_cast(float, u & 0xffff0000u);
            s = fmaf(lo, lo, fmaf(hi, hi, s));
        }
        s += __shfl_xor(s, 1); s += __shfl_xor(s, 2);
        s += __shfl_xor(s, 4); s += __shfl_xor(s, 8);
        if (cs == 0) sq[(size_t)(b * TPLANE + h * W_N + w0 + wr)] = s;
    }
}

// ---------------- Pass B: block=(b,h,wtg) x ig; LDS-staged B tiles ---------
#define MFMA_B16 __builtin_amdgcn_mfma_f32_16x16x32_bf16

__global__ __launch_bounds__(256, 4)
void corrcost9(const unsigned char* __restrict__ ws, float* __restrict__ out)
{
    __shared__ unsigned char stageB[6 * 4096];   // 6 qtiles x 4KB = 24 KiB
    __shared__ float lds[4][16][12];             // extract transpose, 3 KiB

    const int tid  = threadIdx.x;
    const int lane = tid & 63;
    const int wv   = tid >> 6;
    const int col  = lane & 15;
    const int grp  = lane >> 4;

    // x: 1152 blocks = 8 XCDs x 144 (bijective chunked swizzle); y: ig (0..2)
    const int blk = blockIdx.x;
    const int swz = (blk & 7) * 144 + (blk >> 3);   // (b*96+h)*3 + wtg
    const int ig  = blockIdx.y;
    const int wtg = swz % 3;
    const int v3  = swz / 3;
    const int h   = v3 % 96;
    const int b   = v3 / 96;
    const int bT  = b * TPLANE;

    const int wt0 = wtg * 4;
    const int wt  = wt0 + wv;
    const int w0  = wt * 16;

    // A fragments: 4 fully-coalesced 1KB loads (per wave, its own wt)
    const unsigned char* fA = ws + REFF_OFF
        + ((size_t)(b * H_N + h) * 12 + wt) * 4096 + (size_t)lane * 16;
    const s16x8 A0 = *(const s16x8*)(fA);
    const s16x8 A1 = *(const s16x8*)(fA + 1024);
    const s16x8 A2 = *(const s16x8*)(fA + 2048);
    const s16x8 A3 = *(const s16x8*)(fA + 3072);

    const float* r2p = (const float*)(ws + R2_OFF) + bT + h * W_N + w0;
    const f32x4 r2v = *(const f32x4*)(r2p + grp * 4);

    const float* t2pl = (const float*)(ws + T2_OFF) + bT;
    const unsigned char* tgtF = ws + TGTF_OFF;

    float* outb = out + (size_t)b * 81 * TPLANE + (size_t)ig * 27 * TPLANE
                + h * W_N + w0;
    const size_t so0 = (size_t)grp * TPLANE + col;        // j=grp
    const size_t so1 = (size_t)(4 + grp) * TPLANE + col;  // j=4+grp
    const size_t so2 = (size_t)8 * TPLANE + col;          // j=8

    const int rowbase = h + ig * 3 - 4;
    const bool dok0 = (wt >= 1);
    const bool dok2 = (wt <= 10);

#pragma unroll
    for (int tt = 0; tt < 3; ++tt) {
        const int row = rowbase + tt;
        const bool rok = (unsigned)row < (unsigned)H_N;   // block-uniform

        // ---- stage the 6-qtile union for this row (cooperative DMA) ----
        if (rok) {
            const unsigned char* fB = tgtF + (size_t)(b * H_N + row) * FRAG_ROW_SZ;
            {
                const int qt = wt0 - 1 + wv;              // slots 0..3
                if ((unsigned)qt < 12u) {
                    const unsigned char* gp = fB + (size_t)qt * 4096 + (size_t)lane * 16;
                    unsigned char* lp = stageB + wv * 4096;
                    GLL16(gp,        lp);
                    GLL16(gp + 1024, lp + 1024);
                    GLL16(gp + 2048, lp + 2048);
                    GLL16(gp + 3072, lp + 3072);
                }
            }
            if (wv < 2) {                                  // slots 4..5
                const int qt = wt0 + 3 + wv;
                if ((unsigned)qt < 12u) {
                    const unsigned char* gp = fB + (size_t)qt * 4096 + (size_t)lane * 16;
                    unsigned char* lp = stageB + (4 + wv) * 4096;
                    GLL16(gp,        lp);
                    GLL16(gp + 1024, lp + 1024);
                    GLL16(gp + 2048, lp + 2048);
                    GLL16(gp + 3072, lp + 3072);
                }
            }
        }
        __syncthreads();                 // drains vmcnt -> staged data visible

        // ---- compute from LDS ----
        f32x4 acc[3];
        acc[0] = (f32x4){0.f, 0.f, 0.f, 0.f};
        acc[1] = acc[0];
        acc[2] = acc[0];
        float t2v[3] = {0.f, 0.f, 0.f};

        if (rok) {
            const float* t2r = t2pl + row * W_N;
#pragma unroll
            for (int d = 0; d < 3; ++d) {
                const bool dok = (d == 0) ? dok0 : ((d == 1) ? true : dok2);
                if (dok) {                // wave-uniform
                    const unsigned char* p = stageB + (size_t)(wv + d) * 4096
                                           + (size_t)lane * 16;
                    const s16x8 B0 = *(const s16x8*)(p);
                    const s16x8 B1 = *(const s16x8*)(p + 1024);
                    const s16x8 B2 = *(const s16x8*)(p + 2048);
                    const s16x8 B3 = *(const s16x8*)(p + 3072);
                    t2v[d] = t2r[(wt - 1 + d) * 16 + col];
                    acc[d] = MFMA_B16(A0, B0, acc[d], 0, 0, 0);
                    acc[d] = MFMA_B16(A1, B1, acc[d], 0, 0, 0);
                    acc[d] = MFMA_B16(A2, B2, acc[d], 0, 0, 0);
                    acc[d] = MFMA_B16(A3, B3, acc[d], 0, 0, 0);
                }
            }
        }

        // ---- extract: D col = lane&15 (q in tile), D row = grp*4+pp (w) ----
#pragma unroll
        for (int d = 0; d < 3; ++d) {
            const bool dok = (d == 0) ? dok0 : ((d == 1) ? true : dok2);
#pragma unroll
            for (int pp = 0; pp < 4; ++pp) {
                const int wl = grp * 4 + pp;
                const int j  = 16 * (d - 1) + col - wl + 4;
                if ((unsigned)j < 9u) {
                    float val = 0.f;
                    if (rok && dok) {
                        float cs = r2v[pp] + t2v[d] - 2.f * acc[d][pp];
                        val = __builtin_amdgcn_sqrtf(fmaxf(cs, 0.f));
                    }
                    lds[wv][wl][j] = val;
                }
            }
        }

        float* ob = outb + (size_t)tt * 9 * TPLANE;
        float v0 = lds[wv][col][grp];
        float v1 = lds[wv][col][4 + grp];
        ob[so0] = v0;
        ob[so1] = v1;
        if (lane < 16) ob[so2] = lds[wv][col][8];

        __syncthreads();                 // protect stageB before next-row DMA
    }
}

// ---------------- Fallback (round-3 kernel, used if ws too small) ----------
__global__ __launch_bounds__(256, 4)
void corrcost3(const float* __restrict__ ref,
               const float* __restrict__ tgt,
               float* __restrict__ out)
{
    const int tid  = threadIdx.x;
    const int lane = tid & 63;
    const int wv   = tid >> 6;
    const int bid = blockIdx.x;
    const int swz = (bid & 7) * 1296 + (bid >> 3);
    const int u   = swz * 4 + wv;
    const int i   = u % 9;
    const int v9  = u / 9;
    const int wt  = v9 % 12;
    const int v12 = v9 / 12;
    const int h   = v12 % 96;
    const int b   = v12 / 96;
    const int w0  = wt * 16;
    const int q0  = w0 - 8;
    const int row = h + i - 4;
    const bool rok = (unsigned)row < (unsigned)H_N;

    const float* ref_b = ref + (size_t)b * CPLANE;
    const float* tgt_b = tgt + (size_t)b * CPLANE;
    float* out_b = out + (size_t)b * 81 * TPLANE;
    const int col = lane & 15;
    const int ke  = (lane >> 4) * 8;

    s16x8 A[4];
    float r2p = 0.f;
    const float* aptr = ref_b + (size_t)ke * TPLANE + h * W_N + w0 + col;
#pragma unroll
    for (int kc = 0; kc < 4; ++kc) {
#pragma unroll
        for (int e = 0; e < 8; ++e) {
            float v = aptr[(size_t)(kc * 32 + e) * TPLANE];
            short s = f2bf(v);
            float vb = bf2f(s);
            r2p = fmaf(vb, vb, r2p);
            A[kc][e] = s;
        }
    }
    r2p += __shfl_xor(r2p, 16);
    r2p += __shfl_xor(r2p, 32);
    float r2r[4];
#pragma unroll
    for (int pp = 0; pp < 4; ++pp)
        r2r[pp] = __shfl(r2p, (lane >> 4) * 4 + pp);

    f32x4 acc0 = {0.f, 0.f, 0.f, 0.f}, acc1 = acc0;
    float t20 = 0.f, t21 = 0.f;
    if (rok) {
        const float* bbase = tgt_b + (size_t)ke * TPLANE + (size_t)row * W_N;
#pragma unroll
        for (int t = 0; t < 2; ++t) {
            const int q = q0 + t * 16 + col;
            const bool qok = (unsigned)q < (unsigned)W_N;
            const float* bptr = bbase + q;
            s16x8 Bf[4];
            float t2p = 0.f;
#pragma unroll
            for (int kc = 0; kc < 4; ++kc) {
#pragma unroll
                for (int e = 0; e < 8; ++e) {
                    float v = qok ? bptr[(size_t)(kc * 32 + e) * TPLANE] : 0.f;
                    short s = f2bf(v);
                    float vb = bf2f(s);
                    t2p = fmaf(vb, vb, t2p);
                    Bf[kc][e] = s;
                }
            }
            t2p += __shfl_xor(t2p, 16);
            t2p += __shfl_xor(t2p, 32);
            if (t == 0) {
                t20 = t2p;
#pragma unroll
                for (int kc = 0; kc < 4; ++kc)
                    acc0 = MFMA_B16(A[kc], Bf[kc], acc0, 0, 0, 0);
            } else {
                t21 = t2p;
#pragma unroll
                for (int kc = 0; kc < 4; ++kc)
                    acc1 = MFMA_B16(A[kc], Bf[kc], acc1, 0, 0, 0);
            }
        }
    }
#pragma unroll
    for (int t = 0; t < 2; ++t) {
        const int q = q0 + t * 16 + col;
        const bool qok = (unsigned)q < (unsigned)W_N;
        const f32x4 a = t ? acc1 : acc0;
        const float t2 = t ? t21 : t20;
#pragma unroll
        for (int pp = 0; pp < 4; ++pp) {
            const int wl = (lane >> 4) * 4 + pp;
            const int j  = q - (w0 + wl) + 4;
            if ((unsigned)j < 9u) {
                float val = 0.f;
                if (rok && qok) {
                    float cs = r2r[pp] + t2 - 2.f * a[pp];
                    val = cs > 0.f ? sqrtf(cs) : 0.f;
                }
                out_b[(size_t)(i * 9 + j) * TPLANE + h * W_N + w0 + wl] = val;
            }
        }
    }
}

extern "C" void kernel_launch(void* const* d_in, const int* in_sizes, int n_in,
                              void* d_out, int out_size, void* d_ws, size_t ws_size,
                              hipStream_t stream) {
    const float* ref = (const float*)d_in[0];
    const float* tgt = (const float*)d_in[1];
    float* out = (float*)d_out;

    if (ws_size >= WS_NEED && d_ws != nullptr) {
        unsigned char* ws = (unsigned char*)d_ws;
        convert_frag<<<dim3(3 * H_N * B_N, 2), dim3(256), 0, stream>>>(ref, tgt, ws);
        corrcost9<<<dim3(1152, 3), dim3(256), 0, stream>>>(ws, out);
    } else {
        corrcost3<<<dim3(10368), dim3(256), 0, stream>>>(ref, tgt, out);
    }
}